// Round 8
// baseline (303.425 us; speedup 1.0000x reference)
//
#include <hip/hip_runtime.h>
#include <hip/hip_fp16.h>

// FairINV 2-layer GCN + linear head.
// Two-pass binned CSR build (coarse buckets -> LDS-cursor scatter, fused deg/dinv),
// packed 4B CSR {src:u16, ew:f16}, bf16 gathered operand,
// split-bf16 MFMA GEMMs (hi/lo 2-term), gather1 fused into GEMM-2.
// N=50000 nodes, E=800000 edges, IN=256, HID=128, OUT=1.

typedef __attribute__((ext_vector_type(8))) short short8v;  // 8 bf16 = 4 VGPR
typedef __attribute__((ext_vector_type(4))) float f32x4;    // MFMA acc

static constexpr int NN  = 50000;
static constexpr int NE  = 800000;
static constexpr int IND = 256;
static constexpr int HD  = 128;
static constexpr int NNP = 50048;   // padded node count
static constexpr int CAP = 48;      // max degree capacity (Poisson(16): P(>=48)~4e-31)

static constexpr int NB   = 196;    // coarse buckets (dst >> 8)
static constexpr int BCAP = 6144;   // bucket capacity (mean 4096, +32 sigma)

// f32 -> bf16 bits, round-to-nearest-even
__device__ __forceinline__ ushort bf16_rne(float f) {
    uint u = __float_as_uint(f);
    u += 0x7FFFu + ((u >> 16) & 1u);
    return (ushort)(u >> 16);
}
__device__ __forceinline__ float b2f(ushort u) {
    return __uint_as_float((uint)u << 16);
}
__device__ __forceinline__ float f16tof(ushort u) {
    __half h;
    __builtin_memcpy(&h, &u, 2);
    return __half2float(h);
}
__device__ __forceinline__ ushort ftof16(float f) {
    __half h = __float2half_rn(f);
    ushort u;
    __builtin_memcpy(&u, &h, 2);
    return u;
}

// ---------------- prep: weight split + bucket-cursor zero (one launch) ----------------

static constexpr int W1N = IND * HD;   // 32768
static constexpr int W2N = HD * HD;    // 16384

__global__ void prep_kernel(const float* __restrict__ W1, const float* __restrict__ W2,
                            ushort* __restrict__ w1h, ushort* __restrict__ w1l,
                            ushort* __restrict__ w2h, ushort* __restrict__ w2l,
                            int* __restrict__ bcur) {
    int idx = blockIdx.x * 256 + threadIdx.x;
    if (idx < W1N) {
        int k = idx >> 7, c = idx & 127;
        float v = W1[idx];
        ushort hb = bf16_rne(v);
        w1h[(size_t)c * IND + k] = hb;
        w1l[(size_t)c * IND + k] = bf16_rne(v - b2f(hb));
    } else if (idx < W1N + W2N) {
        int i = idx - W1N;
        int k = i >> 7, c = i & 127;
        float v = W2[i];
        ushort hb = bf16_rne(v);
        w2h[(size_t)c * HD + k] = hb;
        w2l[(size_t)c * HD + k] = bf16_rne(v - b2f(hb));
    } else if (idx < W1N + W2N + NB * 16) {
        bcur[idx - W1N - W2N] = 0;
    }
}

// ---------------- pass 1: bin edges into coarse buckets ----------------
// record: x = src(16) | dst_local(8)<<16 ; y = ew_f16

__global__ __launch_bounds__(256) void binpass1(const int* __restrict__ src,
                                                const int* __restrict__ dst,
                                                const float* __restrict__ ew,
                                                int* __restrict__ bcur,
                                                uint2* __restrict__ bins) {
    for (int e = blockIdx.x * 256 + (int)threadIdx.x; e < NE; e += (int)gridDim.x * 256) {
        int d = dst[e];
        int b = d >> 8;
        int pos = atomicAdd(&bcur[b << 4], 1);   // 64B-padded cursor line per bucket
        if (pos < BCAP)
            bins[(size_t)b * BCAP + pos] =
                make_uint2((uint)src[e] | (((uint)d & 255u) << 16), (uint)ftof16(ew[e]));
    }
}

// ---------------- pass 2: per-bucket LDS-cursor scatter + deg/dinv ----------------

__global__ __launch_bounds__(256) void binpass2(const int* __restrict__ bcur,
                                                const uint2* __restrict__ bins,
                                                uint* __restrict__ csr,
                                                int* __restrict__ cursor,
                                                float* __restrict__ dinv) {
    __shared__ int   lcur[256];
    __shared__ float ldeg[256];
    const int b = blockIdx.x, t = threadIdx.x;
    lcur[t] = 0;
    ldeg[t] = 0.f;
    __syncthreads();
    const int cnt = min(bcur[b << 4], BCAP);
    for (int e = t; e < cnt; e += 256) {
        uint2 r = bins[(size_t)b * BCAP + e];
        int dloc = (r.x >> 16) & 255;
        int pos = atomicAdd(&lcur[dloc], 1);
        if (pos < CAP)
            csr[(size_t)(b * 256 + dloc) * CAP + pos] = (r.x & 0xFFFFu) | (r.y << 16);
        atomicAdd(&ldeg[dloc], f16tof((ushort)r.y));
    }
    __syncthreads();
    const int node = b * 256 + t;
    if (node < NN) {
        cursor[node] = min(lcur[t], CAP);
        dinv[node] = rsqrtf(ldeg[t] + 1.0f);
    }
}

// ---------------- shared gather core: (ax,ay) = sum_e w_e * hb[src_e][2lane..2lane+1] --

__device__ __forceinline__ float2 gather_node(int node, int lane,
                                              const ushort* __restrict__ hb,
                                              const float* __restrict__ dinv,
                                              const int* __restrict__ cursor,
                                              const uint* __restrict__ csr) {
    int cnt = min(cursor[node], CAP);
    const uint* row = csr + (size_t)node * CAP;
    float ax = 0.f, ay = 0.f;
    int j = 0;
    for (; j + 4 <= cnt; j += 4) {
        uint4 q = *(const uint4*)(row + j);
        int   s0 = q.x & 0xFFFF,  s1 = q.y & 0xFFFF,  s2 = q.z & 0xFFFF,  s3 = q.w & 0xFFFF;
        float w0 = f16tof((ushort)(q.x >> 16)) * dinv[s0];
        float w1 = f16tof((ushort)(q.y >> 16)) * dinv[s1];
        float w2 = f16tof((ushort)(q.z >> 16)) * dinv[s2];
        float w3 = f16tof((ushort)(q.w >> 16)) * dinv[s3];
        ushort2 v0 = *((const ushort2*)(hb + (size_t)s0 * HD) + lane);
        ushort2 v1 = *((const ushort2*)(hb + (size_t)s1 * HD) + lane);
        ushort2 v2 = *((const ushort2*)(hb + (size_t)s2 * HD) + lane);
        ushort2 v3 = *((const ushort2*)(hb + (size_t)s3 * HD) + lane);
        ax += b2f(v0.x) * w0 + b2f(v1.x) * w1 + b2f(v2.x) * w2 + b2f(v3.x) * w3;
        ay += b2f(v0.y) * w0 + b2f(v1.y) * w1 + b2f(v2.y) * w2 + b2f(v3.y) * w3;
    }
    for (; j < cnt; j++) {
        uint q = row[j];
        int s0 = q & 0xFFFF;
        float w0 = f16tof((ushort)(q >> 16)) * dinv[s0];
        ushort2 v0 = *((const ushort2*)(hb + (size_t)s0 * HD) + lane);
        ax += b2f(v0.x) * w0;
        ay += b2f(v0.y) * w0;
    }
    return make_float2(ax, ay);
}

// ---------------- split-bf16 MFMA GEMM-1: hb[M][128] = bf16(x[M][256] @ W1) ----------
// 256 threads = 4 waves (2x2), wave tile 64x64, block tile 128x128, BK=32.

template<int K>
__global__ __launch_bounds__(256, 2) void gemm_mfma(
        const float* __restrict__ A, const ushort* __restrict__ Bt_hi,
        const ushort* __restrict__ Bt_lo, ushort* __restrict__ Cb, int M) {
    constexpr int BM = 128, LDT = 40;   // 80 B row stride: 16B-aligned, 2-way banks
    __shared__ ushort a_hi[BM * LDT], a_lo[BM * LDT];
    __shared__ ushort b_hi[HD * LDT], b_lo[HD * LDT];

    const int tid  = threadIdx.x;
    const int lane = tid & 63;
    const int wid  = tid >> 6;
    const int wr   = (wid >> 1) << 6;
    const int wc   = (wid & 1) << 6;
    const int row0 = blockIdx.x * BM;

    const int l15 = lane & 15;
    const int kb  = (lane >> 4) << 3;

    const int arow = tid >> 3;
    const int aseg = (tid & 7) << 2;
    const int bcol = tid >> 1;
    const int bko  = (tid & 1) << 4;

    f32x4 acc[4][4] = {};

    for (int k0 = 0; k0 < K; k0 += 32) {
        if (k0) __syncthreads();
#pragma unroll
        for (int p = 0; p < 4; p++) {
            const int r = arow + (p << 5);
            const int grow = row0 + r;
            float4 v = make_float4(0.f, 0.f, 0.f, 0.f);
            if (grow < M) v = *(const float4*)(A + (size_t)grow * K + k0 + aseg);
            ushort h0 = bf16_rne(v.x), h1 = bf16_rne(v.y);
            ushort h2 = bf16_rne(v.z), h3 = bf16_rne(v.w);
            ushort l0 = bf16_rne(v.x - b2f(h0));
            ushort l1 = bf16_rne(v.y - b2f(h1));
            ushort l2 = bf16_rne(v.z - b2f(h2));
            ushort l3 = bf16_rne(v.w - b2f(h3));
            *(ushort4*)(a_hi + r * LDT + aseg) = make_ushort4(h0, h1, h2, h3);
            *(ushort4*)(a_lo + r * LDT + aseg) = make_ushort4(l0, l1, l2, l3);
        }
        {
            const ushort* gh = Bt_hi + (size_t)bcol * K + k0 + bko;
            const ushort* gl = Bt_lo + (size_t)bcol * K + k0 + bko;
            int4 uh0 = *(const int4*)gh;
            int4 uh1 = *(const int4*)(gh + 8);
            int4 ul0 = *(const int4*)gl;
            int4 ul1 = *(const int4*)(gl + 8);
            *(int4*)(b_hi + bcol * LDT + bko)     = uh0;
            *(int4*)(b_hi + bcol * LDT + bko + 8) = uh1;
            *(int4*)(b_lo + bcol * LDT + bko)     = ul0;
            *(int4*)(b_lo + bcol * LDT + bko + 8) = ul1;
        }
        __syncthreads();

        short8v ah[4], al[4], bh[4], bl[4];
#pragma unroll
        for (int m = 0; m < 4; m++) {
            const int r = wr + (m << 4) + l15;
            ah[m] = *(const short8v*)(a_hi + r * LDT + kb);
            al[m] = *(const short8v*)(a_lo + r * LDT + kb);
        }
#pragma unroll
        for (int n = 0; n < 4; n++) {
            const int c = wc + (n << 4) + l15;
            bh[n] = *(const short8v*)(b_hi + c * LDT + kb);
            bl[n] = *(const short8v*)(b_lo + c * LDT + kb);
        }

#pragma unroll
        for (int m = 0; m < 4; m++)
#pragma unroll
            for (int n = 0; n < 4; n++) {
                acc[m][n] = __builtin_amdgcn_mfma_f32_16x16x32_bf16(ah[m], bh[n], acc[m][n], 0, 0, 0);
                acc[m][n] = __builtin_amdgcn_mfma_f32_16x16x32_bf16(ah[m], bl[n], acc[m][n], 0, 0, 0);
                acc[m][n] = __builtin_amdgcn_mfma_f32_16x16x32_bf16(al[m], bh[n], acc[m][n], 0, 0, 0);
            }
    }

#pragma unroll
    for (int m = 0; m < 4; m++) {
#pragma unroll
        for (int r = 0; r < 4; r++) {
            const int grow = row0 + wr + (m << 4) + ((lane >> 4) << 2) + r;
            if (grow < M) {
                ushort* cp = Cb + (size_t)grow * HD + wc + l15;
#pragma unroll
                for (int n = 0; n < 4; n++) cp[n << 4] = bf16_rne(acc[m][n][r]);
            }
        }
    }
}

// ---------------- fused: gather-agg(layer1) -> LDS A-tile -> GEMM-2 -> hb2 -----------
// Block = 128 nodes. Phase 1: each wave gathers 32 nodes' agg rows (f32) and writes
// hi/lo bf16 into LDS [128][LDT=136]. Phase 2: MFMA vs W2 fragments read from global.

__global__ __launch_bounds__(256, 2) void agg_gemm2_kernel(
        const ushort* __restrict__ hb, const float* __restrict__ dinv,
        const int* __restrict__ cursor, const uint* __restrict__ csr,
        const float* __restrict__ b1, const ushort* __restrict__ w2h,
        const ushort* __restrict__ w2l, ushort* __restrict__ hb2) {
    constexpr int LDT = 136;   // 272 B row stride: 16B-aligned, 2-way banks on frag reads
    __shared__ ushort a_hi[128 * LDT], a_lo[128 * LDT];

    const int tid  = threadIdx.x;
    const int lane = tid & 63;
    const int wid  = tid >> 6;
    const int row0 = blockIdx.x * 128;

    // ---- phase 1: gather ----
    for (int i = 0; i < 32; i++) {
        const int r = wid * 32 + i;
        const int node = row0 + r;
        if (node >= NN) break;
        float2 a = gather_node(node, lane, hb, dinv, cursor, csr);
        float dv = dinv[node], d2 = dv * dv;
        ushort2 hv = *((const ushort2*)(hb + (size_t)node * HD) + lane);
        float2 bv = ((const float2*)b1)[lane];
        float fx = a.x * dv + b2f(hv.x) * d2 + bv.x;
        float fy = a.y * dv + b2f(hv.y) * d2 + bv.y;
        ushort hx = bf16_rne(fx), hy = bf16_rne(fy);
        ushort lx = bf16_rne(fx - b2f(hx)), ly = bf16_rne(fy - b2f(hy));
        *(ushort2*)(a_hi + r * LDT + 2 * lane) = make_ushort2(hx, hy);
        *(ushort2*)(a_lo + r * LDT + 2 * lane) = make_ushort2(lx, ly);
    }
    __syncthreads();

    // ---- phase 2: GEMM (K = 128) ----
    const int wr  = (wid >> 1) << 6;
    const int wc  = (wid & 1) << 6;
    const int l15 = lane & 15;
    const int kb  = (lane >> 4) << 3;

    f32x4 acc[4][4] = {};

#pragma unroll
    for (int k0 = 0; k0 < HD; k0 += 32) {
        short8v ah[4], al[4], bh[4], bl[4];
#pragma unroll
        for (int m = 0; m < 4; m++) {
            const int r = wr + (m << 4) + l15;
            ah[m] = *(const short8v*)(a_hi + r * LDT + k0 + kb);
            al[m] = *(const short8v*)(a_lo + r * LDT + k0 + kb);
        }
#pragma unroll
        for (int n = 0; n < 4; n++) {
            const int c = wc + (n << 4) + l15;
            bh[n] = *(const short8v*)(w2h + (size_t)c * HD + k0 + kb);
            bl[n] = *(const short8v*)(w2l + (size_t)c * HD + k0 + kb);
        }
#pragma unroll
        for (int m = 0; m < 4; m++)
#pragma unroll
            for (int n = 0; n < 4; n++) {
                acc[m][n] = __builtin_amdgcn_mfma_f32_16x16x32_bf16(ah[m], bh[n], acc[m][n], 0, 0, 0);
                acc[m][n] = __builtin_amdgcn_mfma_f32_16x16x32_bf16(ah[m], bl[n], acc[m][n], 0, 0, 0);
                acc[m][n] = __builtin_amdgcn_mfma_f32_16x16x32_bf16(al[m], bh[n], acc[m][n], 0, 0, 0);
            }
    }

#pragma unroll
    for (int m = 0; m < 4; m++) {
#pragma unroll
        for (int r = 0; r < 4; r++) {
            const int grow = row0 + wr + (m << 4) + ((lane >> 4) << 2) + r;
            if (grow < NN) {
                ushort* cp = hb2 + (size_t)grow * HD + wc + l15;
#pragma unroll
                for (int n = 0; n < 4; n++) cp[n << 4] = bf16_rne(acc[m][n][r]);
            }
        }
    }
}

// ---------------- gather aggregation (layer 2) + classifier head fused ----------------

__global__ __launch_bounds__(256) void gather_head_kernel(
        const ushort* __restrict__ hb, const float* __restrict__ dinv,
        const int* __restrict__ cursor, const uint* __restrict__ csr,
        const float* __restrict__ b2, const float* __restrict__ Wc,
        const float* __restrict__ bc, float* __restrict__ out) {
    int node = blockIdx.x * 4 + (threadIdx.x >> 6);
    int lane = threadIdx.x & 63;
    if (node >= NN) return;
    float2 a = gather_node(node, lane, hb, dinv, cursor, csr);
    float dv = dinv[node], d2 = dv * dv;
    ushort2 hv = *((const ushort2*)(hb + (size_t)node * HD) + lane);
    float2 bv = ((const float2*)b2)[lane];
    float2 wv = ((const float2*)Wc)[lane];
    float p = (a.x * dv + b2f(hv.x) * d2 + bv.x) * wv.x
            + (a.y * dv + b2f(hv.y) * d2 + bv.y) * wv.y;
#pragma unroll
    for (int off = 32; off; off >>= 1) p += __shfl_down(p, off);
    if (lane == 0) out[node] = p + bc[0];
}

// ---------------- launch ----------------

extern "C" void kernel_launch(void* const* d_in, const int* in_sizes, int n_in,
                              void* d_out, int out_size, void* d_ws, size_t ws_size,
                              hipStream_t stream) {
    const float* x   = (const float*)d_in[0];
    const int*   ei  = (const int*)d_in[1];     // [2][E] int32
    const float* ew  = (const float*)d_in[2];
    const float* W1  = (const float*)d_in[3];
    const float* b1  = (const float*)d_in[4];
    const float* W2  = (const float*)d_in[5];
    const float* b2  = (const float*)d_in[6];
    const float* Wc  = (const float*)d_in[7];
    const float* bc  = (const float*)d_in[8];
    const int* src = ei;
    const int* dst = ei + NE;
    float* out = (float*)d_out;

    // workspace layout (~45.5 MB)
    float*  dinv   = (float*)d_ws;                      // NNP f32
    int*    cursor = (int*)(dinv + NNP);                // NNP int
    uint*   csr    = (uint*)(cursor + NNP);             // NN*CAP uint (9.6 MB)
    ushort* hb     = (ushort*)(csr + (size_t)NN * CAP); // NN*HD bf16 (12.8 MB)
    ushort* hb2    = hb + (size_t)NN * HD;              // NN*HD bf16 (12.8 MB)
    uint2*  bins   = (uint2*)(hb2 + (size_t)NN * HD);   // NB*BCAP uint2 (9.6 MB)
    int*    bcur   = (int*)(bins + (size_t)NB * BCAP);  // NB*16 int (padded cursors)
    ushort* w1h    = (ushort*)(bcur + NB * 16);         // 128*256
    ushort* w1l    = w1h + HD * IND;                    // 128*256
    ushort* w2h    = w1l + HD * IND;                    // 128*128
    ushort* w2l    = w2h + HD * HD;                     // 128*128

    // ---- prep (weight split + bucket-cursor zero) ----
    prep_kernel<<<(W1N + W2N + NB * 16 + 255) / 256, 256, 0, stream>>>(
        W1, W2, w1h, w1l, w2h, w2l, bcur);

    // ---- CSR build: two-pass binning (fused deg/dinv) ----
    binpass1<<<1024, 256, 0, stream>>>(src, dst, ew, bcur, bins);
    binpass2<<<NB, 256, 0, stream>>>(bcur, bins, csr, cursor, dinv);

    // ---- layer 1 dense: hb = bf16(x @ W1) ----
    gemm_mfma<IND><<<(NN + 127) / 128, 256, 0, stream>>>(x, w1h, w1l, hb, NN);

    // ---- layer-1 aggregation fused with GEMM-2: hb2 = bf16(agg(hb) @ W2) ----
    agg_gemm2_kernel<<<(NN + 127) / 128, 256, 0, stream>>>(
        hb, dinv, cursor, csr, b1, w2h, w2l, hb2);

    // ---- layer-2 aggregation + head ----
    gather_head_kernel<<<(NN + 3) / 4, 256, 0, stream>>>(
        hb2, dinv, cursor, csr, b2, Wc, bc, out);
}

// Round 9
// 108.566 us; speedup vs baseline: 2.7948x; 2.7948x over previous
//
#include <hip/hip_runtime.h>
#include <hip/hip_fp16.h>

// FairINV 2-layer GCN + linear head — FULLY LINEAR COLLAPSE.
// No activation anywhere and OUT=1, so P(H)@Wc = P(H@Wc) folds the whole net:
//   w2c = W2@Wc; w1c = W1@w2c; c1 = b1.w2c; c2 = b2.Wc + bc
//   z0 = x@w1c (GEMV);  z1 = P(z0)+c1;  out = P(z1)+c2
// where P(z)[n] = dinv[n]*sum_e(ew_e*dinv[src_e]*z[src_e]) + dinv[n]^2*z[n].
// Graph: packed 4B CSR {src:u16, ew:f16} built by atomic-cursor scatter
// (fused with the GEMV — neither uses LDS, so occupancy stays high).
// N=50000 nodes, E=800000 edges, IN=256, HID=128, OUT=1.

static constexpr int NN  = 50000;
static constexpr int NE  = 800000;
static constexpr int IND = 256;
static constexpr int HD  = 128;
static constexpr int NNP = 50048;   // padded node count
static constexpr int CAP = 48;      // max in-degree capacity (Poisson(16): P(>=48)~4e-31)

static constexpr int GEMV_BLOCKS = 3125;   // 16 nodes/block (4 waves x 4 nodes)
static constexpr int SCAT_BLOCKS = (NE + 255) / 256;   // 3125

__device__ __forceinline__ float f16tof(ushort u) {
    __half h;
    __builtin_memcpy(&h, &u, 2);
    return __half2float(h);
}
__device__ __forceinline__ ushort ftof16(float f) {
    __half h = __float2half_rn(f);
    ushort u;
    __builtin_memcpy(&u, &h, 2);
    return u;
}

// ---------------- prep: fold weights (one block) ----------------
// w2c[k] = sum_j W2[k][j]*Wc[j];  w1c[i] = sum_k W1[i][k]*w2c[k];
// consts = {c1 = b1.w2c, c2 = b2.Wc + bc}

__global__ __launch_bounds__(256) void prep_kernel(
        const float* __restrict__ W1, const float* __restrict__ b1,
        const float* __restrict__ W2, const float* __restrict__ b2,
        const float* __restrict__ Wc, const float* __restrict__ bc,
        float* __restrict__ w1c, float* __restrict__ consts) {
    __shared__ float s_w2c[HD];
    const int t = threadIdx.x;
    if (t < HD) {
        float s = 0.f;
        for (int j = 0; j < HD; j++) s += W2[t * HD + j] * Wc[j];
        s_w2c[t] = s;
    }
    __syncthreads();
    {   // t in [0,256) == IND
        float s = 0.f;
        for (int k = 0; k < HD; k++) s += W1[t * HD + k] * s_w2c[k];
        w1c[t] = s;
    }
    if (t == 0) {
        float c1 = 0.f, c2 = 0.f;
        for (int k = 0; k < HD; k++) c1 += b1[k] * s_w2c[k];
        for (int j = 0; j < HD; j++) c2 += b2[j] * Wc[j];
        consts[0] = c1;
        consts[1] = c2 + bc[0];
    }
}

// ---------------- fused GEMV (z0 = x @ w1c) + CSR scatter ----------------
// GEMV blocks: one wave per node, lane reads float4 of x-row (64*4 = 256 = IND).
// Scatter blocks: one returning int atomic per edge, 4B packed record.
// No LDS in either branch -> no occupancy coupling (R6/R8 lesson).

__global__ __launch_bounds__(256) void gemv_scatter(
        const float* __restrict__ x, const float* __restrict__ w1c,
        float* __restrict__ z0,
        const int* __restrict__ src, const int* __restrict__ dst,
        const float* __restrict__ ew,
        int* __restrict__ cursor, uint* __restrict__ csr) {
    if (blockIdx.x < GEMV_BLOCKS) {
        const int wid  = threadIdx.x >> 6;
        const int lane = threadIdx.x & 63;
        const int base = blockIdx.x * 16 + wid * 4;
        const float4 wv = ((const float4*)w1c)[lane];
#pragma unroll
        for (int g = 0; g < 4; g++) {
            const int n = base + g;
            if (n >= NN) break;
            const float4 xv = *((const float4*)(x + (size_t)n * IND) + lane);
            float p = xv.x * wv.x + xv.y * wv.y + xv.z * wv.z + xv.w * wv.w;
#pragma unroll
            for (int off = 32; off; off >>= 1) p += __shfl_down(p, off);
            if (lane == 0) z0[n] = p;
        }
    } else {
        const int e = (blockIdx.x - GEMV_BLOCKS) * 256 + (int)threadIdx.x;
        if (e < NE) {
            const int d = dst[e];
            const int pos = atomicAdd(&cursor[d], 1);
            if (pos < CAP)
                csr[(size_t)d * CAP + pos] = (uint)src[e] | ((uint)ftof16(ew[e]) << 16);
        }
    }
}

// ---------------- deg + dinv from packed CSR (no atomics) ----------------

__global__ __launch_bounds__(256) void degdinv_kernel(const uint* __restrict__ csr,
                                                      const int* __restrict__ cursor,
                                                      float* __restrict__ dinv) {
    const int node = blockIdx.x * 4 + (threadIdx.x >> 6);
    const int lane = threadIdx.x & 63;
    if (node >= NN) return;
    const int cnt = min(cursor[node], CAP);
    float v = (lane < cnt) ? f16tof((ushort)(csr[(size_t)node * CAP + lane] >> 16)) : 0.f;
#pragma unroll
    for (int off = 32; off; off >>= 1) v += __shfl_down(v, off);
    if (lane == 0) dinv[node] = rsqrtf(v + 1.0f);
}

// ---------------- scalar propagation: zout = P(zin) + consts[cidx] ----------------
// One wave per node; lane l handles CSR entry l (cnt <= CAP = 48 < 64, single pass).
// zin/dinv are 200 KB arrays -> L2-resident random scalar reads.

__global__ __launch_bounds__(256) void prop_kernel(
        const float* __restrict__ zin, const float* __restrict__ dinv,
        const int* __restrict__ cursor, const uint* __restrict__ csr,
        const float* __restrict__ consts, int cidx, float* __restrict__ zout) {
    const int node = blockIdx.x * 4 + (threadIdx.x >> 6);
    const int lane = threadIdx.x & 63;
    if (node >= NN) return;
    const int cnt = min(cursor[node], CAP);
    float v = 0.f;
    if (lane < cnt) {
        const uint q = csr[(size_t)node * CAP + lane];
        const int s = q & 0xFFFFu;
        v = f16tof((ushort)(q >> 16)) * dinv[s] * zin[s];
    }
#pragma unroll
    for (int off = 32; off; off >>= 1) v += __shfl_down(v, off);
    if (lane == 0) {
        const float dv = dinv[node];
        zout[node] = v * dv + zin[node] * dv * dv + consts[cidx];
    }
}

// ---------------- launch ----------------

extern "C" void kernel_launch(void* const* d_in, const int* in_sizes, int n_in,
                              void* d_out, int out_size, void* d_ws, size_t ws_size,
                              hipStream_t stream) {
    const float* x   = (const float*)d_in[0];
    const int*   ei  = (const int*)d_in[1];     // [2][E] int32
    const float* ew  = (const float*)d_in[2];
    const float* W1  = (const float*)d_in[3];
    const float* b1  = (const float*)d_in[4];
    const float* W2  = (const float*)d_in[5];
    const float* b2  = (const float*)d_in[6];
    const float* Wc  = (const float*)d_in[7];
    const float* bc  = (const float*)d_in[8];
    const int* src = ei;
    const int* dst = ei + NE;
    float* out = (float*)d_out;

    // workspace layout (~10.4 MB)
    float* dinv   = (float*)d_ws;                  // NNP f32
    float* z0     = dinv + NNP;                    // NNP f32
    float* z1     = z0 + NNP;                      // NNP f32
    float* w1c    = z1 + NNP;                      // 256 f32
    float* consts = w1c + 256;                     // 2 f32 {c1, c2}
    int*   cursor = (int*)(consts + 64);           // NNP int
    uint*  csr    = (uint*)(cursor + NNP);         // NN*CAP uint (9.6 MB)

    // ---- fold weights; zero cursors ----
    prep_kernel<<<1, 256, 0, stream>>>(W1, b1, W2, b2, Wc, bc, w1c, consts);
    hipMemsetAsync(cursor, 0, NNP * sizeof(int), stream);

    // ---- z0 = x @ w1c fused with CSR build ----
    gemv_scatter<<<GEMV_BLOCKS + SCAT_BLOCKS, 256, 0, stream>>>(
        x, w1c, z0, src, dst, ew, cursor, csr);

    // ---- dinv from CSR ----
    degdinv_kernel<<<(NN + 3) / 4, 256, 0, stream>>>(csr, cursor, dinv);

    // ---- two scalar propagations ----
    prop_kernel<<<(NN + 3) / 4, 256, 0, stream>>>(z0, dinv, cursor, csr, consts, 0, z1);
    prop_kernel<<<(NN + 3) / 4, 256, 0, stream>>>(z1, dinv, cursor, csr, consts, 1, out);
}

// Round 10
// 66.044 us; speedup vs baseline: 4.5943x; 1.6438x over previous
//
#include <hip/hip_runtime.h>

// FairINV 2-layer GCN + linear head — fully linear collapse + bucket-binned propagation.
//   w2c = W2@Wc; w1c = W1@w2c; c1 = b1.w2c; c2 = b2.Wc + bc
//   z0 = x@w1c (GEMV);  z1 = P(z0)+c1;  out = P(z1)+c2
//   P(z)[n] = dinv[n]*sum_e(ew_e*dinv[src_e]*z[src_e]) + dinv[n]^2*z[n]
// Graph structure: edges binned by bucket = dst>>6 (782 buckets of 64 nodes),
// 8B records {src u16 | dloc u6, ew f32}. Binning is contention-free:
// per-block register staging -> LDS histogram -> one range-reservation atomic per
// (block,bucket) -> near-sequential record writes. Propagation accumulates in a
// 64-slot LDS f32 accumulator per bucket (no per-dst cursors, no global f32 atomics,
// no capacity risk). All arithmetic f32.
// N=50000 nodes, E=800000 edges, IN=256, HID=128, OUT=1.

static constexpr int NN   = 50000;
static constexpr int NE   = 800000;
static constexpr int IND  = 256;
static constexpr int HD   = 128;
static constexpr int NNP  = 50048;

static constexpr int NBUK = 782;            // ceil(NN/64); bucket = dst >> 6
static constexpr int BCAP = 1536;           // mean fill 1024, +16 sigma
static constexpr int BIN_BLOCKS  = 256;
static constexpr int EPB         = NE / BIN_BLOCKS;   // 3125 (exact)
static constexpr int SLOTS       = (EPB + 255) / 256; // 13 register slots/thread
static constexpr int GEMV_BLOCKS = 3125;              // 16 nodes per block

// ---------------- prep: fold weights + zero bucket cursors (one block) ----------------

__global__ __launch_bounds__(256) void prep_kernel(
        const float* __restrict__ W1, const float* __restrict__ b1,
        const float* __restrict__ W2, const float* __restrict__ b2,
        const float* __restrict__ Wc, const float* __restrict__ bc,
        float* __restrict__ w1c, float* __restrict__ consts,
        int* __restrict__ gcur) {
    __shared__ float s_w2c[HD];
    const int t = threadIdx.x;
    for (int i = t; i < NBUK; i += 256) gcur[i] = 0;
    if (t < HD) {
        float s = 0.f;
        for (int j = 0; j < HD; j++) s += W2[t * HD + j] * Wc[j];
        s_w2c[t] = s;
    }
    __syncthreads();
    {   // t in [0,256) == IND
        float s = 0.f;
        for (int k = 0; k < HD; k++) s += W1[t * HD + k] * s_w2c[k];
        w1c[t] = s;
    }
    if (t == 0) {
        float c1 = 0.f, c2 = 0.f;
        for (int k = 0; k < HD; k++) c1 += b1[k] * s_w2c[k];
        for (int j = 0; j < HD; j++) c2 += b2[j] * Wc[j];
        consts[0] = c1;
        consts[1] = c2 + bc[0];
    }
}

// ---------------- fused GEMV (z0 = x @ w1c) + contention-free edge binning ----------
// GEMV blocks: one wave per node, lane reads float4 of the x-row.
// Bin blocks: stage 3125 edges in registers, LDS histogram over 782 buckets,
// reserve ranges (1 global atomic per block-bucket), write 8B records.

__global__ __launch_bounds__(256) void gemv_bin(
        const float* __restrict__ x, const float* __restrict__ w1c,
        float* __restrict__ z0,
        const int* __restrict__ src, const int* __restrict__ dst,
        const float* __restrict__ ew,
        int* __restrict__ gcur, uint2* __restrict__ bins) {
    __shared__ int hist[NBUK];
    __shared__ int cur[NBUK];

    if (blockIdx.x < GEMV_BLOCKS) {
        const int wid  = threadIdx.x >> 6;
        const int lane = threadIdx.x & 63;
        const int base = blockIdx.x * 16 + wid * 4;
        const float4 wv = ((const float4*)w1c)[lane];
#pragma unroll
        for (int g = 0; g < 4; g++) {
            const int n = base + g;
            if (n >= NN) break;
            const float4 xv = *((const float4*)(x + (size_t)n * IND) + lane);
            float p = xv.x * wv.x + xv.y * wv.y + xv.z * wv.z + xv.w * wv.w;
#pragma unroll
            for (int off = 32; off; off >>= 1) p += __shfl_down(p, off);
            if (lane == 0) z0[n] = p;
        }
    } else {
        const int t    = threadIdx.x;
        const int base = (blockIdx.x - GEMV_BLOCKS) * EPB;
        uint  key[SLOTS];
        float wv[SLOTS];
        for (int i = t; i < NBUK; i += 256) hist[i] = 0;
        __syncthreads();
#pragma unroll
        for (int k = 0; k < SLOTS; k++) {
            const int off = k * 256 + t;
            if (off < EPB) {
                const int e = base + off;
                const int d = dst[e];
                const int b = d >> 6;
                key[k] = (uint)src[e] | (((uint)d & 63u) << 16) | ((uint)b << 22);
                wv[k]  = ew[e];
                atomicAdd(&hist[b], 1);
            } else {
                key[k] = 0xFFFFFFFFu;
            }
        }
        __syncthreads();
        for (int i = t; i < NBUK; i += 256) {
            const int h = hist[i];
            cur[i] = h ? atomicAdd(&gcur[i], h) : 0;
        }
        __syncthreads();
#pragma unroll
        for (int k = 0; k < SLOTS; k++) {
            if (key[k] != 0xFFFFFFFFu) {
                const int b = key[k] >> 22;
                const int p = atomicAdd(&cur[b], 1);
                if (p < BCAP)
                    bins[(size_t)b * BCAP + p] =
                        make_uint2(key[k] & 0x3FFFFFu, __float_as_uint(wv[k]));
            }
        }
    }
}

// ---------------- bindeg: bins -> dinv, interleave dz0 = {dinv, z0} ----------------

__global__ __launch_bounds__(256) void bindeg_kernel(
        const int* __restrict__ gcur, const uint2* __restrict__ bins,
        const float* __restrict__ z0, float2* __restrict__ dz0) {
    __shared__ float acc[64];
    const int b = blockIdx.x, t = threadIdx.x;
    if (t < 64) acc[t] = 0.f;
    __syncthreads();
    const int cnt = min(gcur[b], BCAP);
    for (int r = t; r < cnt; r += 256) {
        const uint2 q = bins[(size_t)b * BCAP + r];
        atomicAdd(&acc[(q.x >> 16) & 63u], __uint_as_float(q.y));
    }
    __syncthreads();
    if (t < 64) {
        const int n = b * 64 + t;
        if (n < NN) {
            const float dv = rsqrtf(acc[t] + 1.0f);
            dz0[n] = make_float2(dv, z0[n]);
        }
    }
}

// ---------------- prop: one bucket per block, LDS 64-slot accumulator ----------------
// zout[n] = acc[n]*dinv[n] + z[n]*dinv[n]^2 + consts[cidx]

template<bool LAST>
__global__ __launch_bounds__(256) void prop_kernel(
        const int* __restrict__ gcur, const uint2* __restrict__ bins,
        const float2* __restrict__ dzin, const float* __restrict__ consts,
        int cidx, float2* __restrict__ dzout, float* __restrict__ fout) {
    __shared__ float acc[64];
    const int b = blockIdx.x, t = threadIdx.x;
    if (t < 64) acc[t] = 0.f;
    __syncthreads();
    const int cnt = min(gcur[b], BCAP);
    for (int r = t; r < cnt; r += 256) {
        const uint2 q = bins[(size_t)b * BCAP + r];
        const float2 sz = dzin[q.x & 0xFFFFu];          // {dinv[s], z[s]} — L2-resident
        atomicAdd(&acc[(q.x >> 16) & 63u], __uint_as_float(q.y) * sz.x * sz.y);
    }
    __syncthreads();
    if (t < 64) {
        const int n = b * 64 + t;
        if (n < NN) {
            const float2 me = dzin[n];
            const float v = acc[t] * me.x + me.y * me.x * me.x + consts[cidx];
            if (LAST) fout[n] = v;
            else      dzout[n] = make_float2(me.x, v);
        }
    }
}

// ---------------- launch ----------------

extern "C" void kernel_launch(void* const* d_in, const int* in_sizes, int n_in,
                              void* d_out, int out_size, void* d_ws, size_t ws_size,
                              hipStream_t stream) {
    const float* x   = (const float*)d_in[0];
    const int*   ei  = (const int*)d_in[1];     // [2][E] int32
    const float* ew  = (const float*)d_in[2];
    const float* W1  = (const float*)d_in[3];
    const float* b1  = (const float*)d_in[4];
    const float* W2  = (const float*)d_in[5];
    const float* b2  = (const float*)d_in[6];
    const float* Wc  = (const float*)d_in[7];
    const float* bc  = (const float*)d_in[8];
    const int* src = ei;
    const int* dst = ei + NE;
    float* out = (float*)d_out;

    // workspace layout (~11.1 MB)
    uint2*  bins   = (uint2*)d_ws;                     // NBUK*BCAP uint2 (9.6 MB)
    float2* dz0    = (float2*)(bins + (size_t)NBUK * BCAP);  // NNP float2
    float2* dz1    = dz0 + NNP;                        // NNP float2
    float*  z0     = (float*)(dz1 + NNP);              // NNP f32
    float*  w1c    = z0 + NNP;                         // 256 f32
    float*  consts = w1c + 256;                        // 2 f32 {c1, c2}
    int*    gcur   = (int*)(consts + 64);              // NBUK int

    // ---- fold weights + zero cursors ----
    prep_kernel<<<1, 256, 0, stream>>>(W1, b1, W2, b2, Wc, bc, w1c, consts, gcur);

    // ---- z0 = x @ w1c fused with edge binning ----
    gemv_bin<<<GEMV_BLOCKS + BIN_BLOCKS, 256, 0, stream>>>(
        x, w1c, z0, src, dst, ew, gcur, bins);

    // ---- dinv from bins, build {dinv, z0} ----
    bindeg_kernel<<<NBUK, 256, 0, stream>>>(gcur, bins, z0, dz0);

    // ---- two scalar propagations ----
    prop_kernel<false><<<NBUK, 256, 0, stream>>>(gcur, bins, dz0, consts, 0, dz1, nullptr);
    prop_kernel<true><<<NBUK, 256, 0, stream>>>(gcur, bins, dz1, consts, 1, nullptr, out);
}